// Round 3
// baseline (640.888 us; speedup 1.0000x reference)
//
#include <hip/hip_runtime.h>
#include <hip/hip_bf16.h>
#include <cstddef>
#include <cstdint>

#define BS 32768
#define MSLOT 2048
#define D 256
#define NCHUNK 256   // i-tiles of 128 rows in k_score

typedef _Float16 f16;
typedef _Float16 f16x8 __attribute__((ext_vector_type(8)));
typedef float f32x4 __attribute__((ext_vector_type(4)));

__device__ __forceinline__ void lds_cp16(void* dst, const void* src) {
    __builtin_amdgcn_global_load_lds(
        (const __attribute__((address_space(1))) void*)src,
        (__attribute__((address_space(3))) void*)dst, 16, 0, 0);
}

__device__ __forceinline__ void top2_merge(float& a0, int& ai0, float& a1, int& ai1,
                                           float b0, int bi0, float b1, int bi1)
{
    bool bt = (b0 > a0) || (b0 == a0 && bi0 < ai0);
    float n0, n1; int ni0, ni1;
    if (bt) {
        n0 = b0; ni0 = bi0;
        bool s2 = (b1 > a0) || (b1 == a0 && bi1 < ai0);
        n1 = s2 ? b1 : a0; ni1 = s2 ? bi1 : ai0;
    } else {
        n0 = a0; ni0 = ai0;
        bool s2 = (b0 > a1) || (b0 == a1 && bi0 < ai1);
        n1 = s2 ? b0 : a1; ni1 = s2 ? bi0 : ai1;
    }
    a0 = n0; ai0 = ni0; a1 = n1; ai1 = ni1;
}

// ---------------------------------------------------------------- prep: normalize + f16x2 split (q scaled by 256)
__global__ __launch_bounds__(256) void k_prepq(const float* __restrict__ query,
                                               float* __restrict__ out0,
                                               f16* __restrict__ qh, f16* __restrict__ ql)
{
    __shared__ float sbuf[4];
    const int i = blockIdx.x, t = threadIdx.x;
    float v = query[(size_t)i * D + t];
    float ss = v * v;
#pragma unroll
    for (int off = 32; off; off >>= 1) ss += __shfl_xor(ss, off, 64);
    if ((t & 63) == 0) sbuf[t >> 6] = ss;
    __syncthreads();
    float tot = (sbuf[0] + sbuf[1]) + (sbuf[2] + sbuf[3]);
    float n = fmaxf(sqrtf(tot), 1e-12f);
    float qv = v / n;
    out0[(size_t)i * (2 * D) + t] = qv;
    float qs = qv * 256.0f;
    f16 h = (f16)qs;
    f16 lo = (f16)(qs - (float)h);
    qh[(size_t)i * D + t] = h;
    ql[(size_t)i * D + t] = lo;
}

// ---------------------------------------------------------------- prep: memory split + f16 transpose + zero qupd
__global__ __launch_bounds__(256) void k_prepm(const float* __restrict__ memory,
                                               f16* __restrict__ mh, f16* __restrict__ ml,
                                               f16* __restrict__ memT,
                                               float* __restrict__ qupd)
{
    const int j = blockIdx.x, t = threadIdx.x;
    float m = memory[(size_t)j * D + t];
    f16 h = (f16)m;
    f16 lo = (f16)(m - (float)h);
    mh[(size_t)j * D + t] = h;
    ml[(size_t)j * D + t] = lo;
    memT[(size_t)t * MSLOT + j] = h;   // [n=dim][k=slot]
    qupd[(size_t)j * D + t] = 0.0f;    // zero-init segment-sum buffer (replaces memset)
}

// ---------------------------------------------------------------- score GEMM (f16x2, 3 products) + col partials
// 2-phase double-buffered: stage(next) || ds_read(cur)+MFMA, one barrier per K-step.
__global__ __launch_bounds__(256) void k_score(const f16* __restrict__ qh, const f16* __restrict__ ql,
                                               const f16* __restrict__ mh, const f16* __restrict__ ml,
                                               float* __restrict__ out2,
                                               float* __restrict__ colpart)
{
    __shared__ __align__(16) f16 Ah[2][4096], Al[2][4096], Bh[2][4096], Bl[2][4096];  // 64 KB
    __shared__ float sepM[4][4][16], sepS[4][4][16];
    const int t = threadIdx.x;
    const int l = t & 63, w = t >> 6;
    const int wr = w >> 1, wc = w & 1;
    const int lk = l >> 4, lm = l & 15;
    const int i0 = blockIdx.y * 128, j0 = blockIdx.x * 128;

    f32x4 acc[4][4] = {};

#define STAGE_SCORE(buf, k0)                                                     \
    {                                                                            \
        _Pragma("unroll")                                                        \
        for (int c = 0; c < 2; ++c) {                                            \
            int s = c * 256 + t;                                                 \
            int r = s >> 2, cc = s & 3;                                          \
            int scc = cc ^ ((r >> 1) & 3);                                       \
            size_t aoff = (size_t)(i0 + r) * D + (k0) + scc * 8;                 \
            size_t boff = (size_t)(j0 + r) * D + (k0) + scc * 8;                 \
            lds_cp16(&Ah[buf][s * 8], qh + aoff);                                \
            lds_cp16(&Al[buf][s * 8], ql + aoff);                                \
            lds_cp16(&Bh[buf][s * 8], mh + boff);                                \
            lds_cp16(&Bl[buf][s * 8], ml + boff);                                \
        }                                                                        \
    }

    STAGE_SCORE(0, 0);
    __syncthreads();

    for (int ks = 0; ks < 8; ++ks) {
        const int cur = ks & 1;
        if (ks < 7) STAGE_SCORE(cur ^ 1, (ks + 1) * 32);

        f16x8 a_h[4], a_l[4], b_h[4], b_l[4];
#pragma unroll
        for (int m = 0; m < 4; ++m) {
            int r = wr * 64 + m * 16 + lm;
            int off = r * 64 + ((lk ^ ((r >> 1) & 3)) << 4);
            a_h[m] = *(const f16x8*)((const char*)Ah[cur] + off);
            a_l[m] = *(const f16x8*)((const char*)Al[cur] + off);
        }
#pragma unroll
        for (int n = 0; n < 4; ++n) {
            int r = wc * 64 + n * 16 + lm;
            int off = r * 64 + ((lk ^ ((r >> 1) & 3)) << 4);
            b_h[n] = *(const f16x8*)((const char*)Bh[cur] + off);
            b_l[n] = *(const f16x8*)((const char*)Bl[cur] + off);
        }
#pragma unroll
        for (int m = 0; m < 4; ++m)
#pragma unroll
            for (int n = 0; n < 4; ++n) {
                acc[m][n] = __builtin_amdgcn_mfma_f32_16x16x32_f16(a_h[m], b_h[n], acc[m][n], 0, 0, 0);
                acc[m][n] = __builtin_amdgcn_mfma_f32_16x16x32_f16(a_h[m], b_l[n], acc[m][n], 0, 0, 0);
                acc[m][n] = __builtin_amdgcn_mfma_f32_16x16x32_f16(a_l[m], b_h[n], acc[m][n], 0, 0, 0);
            }
        __syncthreads();   // waits vmcnt(0) (next stage landed) + lgkmcnt, then barrier
    }
#undef STAGE_SCORE

    // scale back (q was pre-scaled by 256)
    const float sc = 1.0f / 256.0f;
#pragma unroll
    for (int m = 0; m < 4; ++m)
#pragma unroll
        for (int n = 0; n < 4; ++n)
            acc[m][n] *= sc;

    // store raw score
#pragma unroll
    for (int m = 0; m < 4; ++m) {
        int row = i0 + wr * 64 + m * 16 + lk * 4;
#pragma unroll
        for (int n = 0; n < 4; ++n) {
            int col = j0 + wc * 64 + n * 16 + lm;
#pragma unroll
            for (int r = 0; r < 4; ++r)
                out2[(size_t)(row + r) * MSLOT + col] = acc[m][n][r];
        }
    }

    // fused column partials (online max+sumexp over this block's 128 rows)
    float cm[4], cs[4];
#pragma unroll
    for (int n = 0; n < 4; ++n) {
        float mx = -INFINITY;
#pragma unroll
        for (int m = 0; m < 4; ++m)
#pragma unroll
            for (int r = 0; r < 4; ++r) mx = fmaxf(mx, acc[m][n][r]);
        float sm = 0.0f;
#pragma unroll
        for (int m = 0; m < 4; ++m)
#pragma unroll
            for (int r = 0; r < 4; ++r) sm += __expf(acc[m][n][r] - mx);
#pragma unroll
        for (int off = 16; off <= 32; off <<= 1) {
            float om = __shfl_xor(mx, off, 64);
            float os = __shfl_xor(sm, off, 64);
            float nm = fmaxf(mx, om);
            sm = sm * __expf(mx - nm) + os * __expf(om - nm);
            mx = nm;
        }
        cm[n] = mx; cs[n] = sm;
    }
    if (l < 16) {
#pragma unroll
        for (int n = 0; n < 4; ++n) { sepM[w][n][l] = cm[n]; sepS[w][n][l] = cs[n]; }
    }
    __syncthreads();
    if (w < 2 && l < 16) {
#pragma unroll
        for (int n = 0; n < 4; ++n) {
            float m1 = sepM[w][n][l], s1 = sepS[w][n][l];
            float m2 = sepM[w + 2][n][l], s2 = sepS[w + 2][n][l];
            float nm = fmaxf(m1, m2);
            float ns = s1 * __expf(m1 - nm) + s2 * __expf(m2 - nm);
            int col = j0 + w * 64 + n * 16 + l;
            size_t o = ((size_t)blockIdx.y * MSLOT + col) * 2;
            colpart[o + 0] = nm;
            colpart[o + 1] = ns;
        }
    }
}

// ---------------------------------------------------------------- column merge
__global__ __launch_bounds__(256) void k_colmerge(const float* __restrict__ colpart,
                                                  float* __restrict__ colM,
                                                  float* __restrict__ colSinv,
                                                  float* __restrict__ colC)
{
    const int col = blockIdx.x * 256 + threadIdx.x;
    float m = -INFINITY, s = 0.0f;
    for (int c = 0; c < NCHUNK; ++c) {
        size_t o = ((size_t)c * MSLOT + col) * 2;
        float pm = colpart[o + 0], ps = colpart[o + 1];
        float nm = fmaxf(m, pm);
        s = s * __expf(m - nm) + ps * __expf(pm - nm);
        m = nm;
    }
    colM[col] = m;
    colSinv[col] = 1.0f / s;
    colC[col] = m + __logf(s);
}

// ---------------------------------------------------------------- fused row pass + softmax transforms (vectorized)
__global__ __launch_bounds__(256) void k_rowtrans(float* __restrict__ sq,   // out2 in-place
                                                  float* __restrict__ sm,   // out3
                                                  f16* __restrict__ pf16,   // sfxm f16 copy
                                                  const float* __restrict__ colM,
                                                  const float* __restrict__ colSinv,
                                                  const float* __restrict__ colC,
                                                  const float* __restrict__ out0,   // q in left half, ld 2D
                                                  const float* __restrict__ memory,
                                                  int* __restrict__ jstarA, float* __restrict__ wA,
                                                  float* __restrict__ gpart, float* __restrict__ spart)
{
    __shared__ float swm[4], sws[4];
    __shared__ float st0v[4], st1v[4]; __shared__ int st0i[4], st1i[4];
    __shared__ float sav[4], sar[4];  __shared__ int sai[4];
    __shared__ float sg[4], sdp[4], sdn[4];

    const int i = blockIdx.x, t = threadIdx.x;
    const int l = t & 63, w = t >> 6;
    const int jb = t * 8;
    float* row = sq + (size_t)i * MSLOT;

    float v[8];
    {
        float4 va = *(const float4*)(row + jb);
        float4 vb = *(const float4*)(row + jb + 4);
        v[0] = va.x; v[1] = va.y; v[2] = va.z; v[3] = va.w;
        v[4] = vb.x; v[5] = vb.y; v[6] = vb.z; v[7] = vb.w;
    }
    float cCv[8], cMv[8], cSv[8];
    {
        float4 a = *(const float4*)(colC + jb);
        float4 b = *(const float4*)(colC + jb + 4);
        cCv[0] = a.x; cCv[1] = a.y; cCv[2] = a.z; cCv[3] = a.w;
        cCv[4] = b.x; cCv[5] = b.y; cCv[6] = b.z; cCv[7] = b.w;
        a = *(const float4*)(colM + jb); b = *(const float4*)(colM + jb + 4);
        cMv[0] = a.x; cMv[1] = a.y; cMv[2] = a.z; cMv[3] = a.w;
        cMv[4] = b.x; cMv[5] = b.y; cMv[6] = b.z; cMv[7] = b.w;
        a = *(const float4*)(colSinv + jb); b = *(const float4*)(colSinv + jb + 4);
        cSv[0] = a.x; cSv[1] = a.y; cSv[2] = a.z; cSv[3] = a.w;
        cSv[4] = b.x; cSv[5] = b.y; cSv[6] = b.z; cSv[7] = b.w;
    }

    // --- row max ---
    float lmx = v[0];
#pragma unroll
    for (int k = 1; k < 8; ++k) lmx = fmaxf(lmx, v[k]);
#pragma unroll
    for (int off = 32; off; off >>= 1) lmx = fmaxf(lmx, __shfl_xor(lmx, off, 64));
    if (l == 0) swm[w] = lmx;
    __syncthreads();
    const float rm = fmaxf(fmaxf(swm[0], swm[1]), fmaxf(swm[2], swm[3]));

    // --- per-thread: sumexp, top2(raw), argmax(col-softmax) ---
    float ls = 0.0f;
#pragma unroll
    for (int k = 0; k < 8; ++k) ls += __expf(v[k] - rm);

    float v0 = -INFINITY, v1 = -INFINITY; int i0 = 0x7fffffff, i1 = 0x7fffffff;
#pragma unroll
    for (int k = 0; k < 8; ++k) {
        int idx = jb + k; float cv = v[k];
        if (cv > v0)      { v1 = v0; i1 = i0; v0 = cv; i0 = idx; }
        else if (cv > v1) { v1 = cv; i1 = idx; }
    }

    float av = -INFINITY, araw = 0.0f; int ai = 0x7fffffff;
#pragma unroll
    for (int k = 0; k < 8; ++k) {
        int idx = jb + k;
        float x = v[k] - cCv[k];
        if (x > av) { av = x; ai = idx; araw = v[k]; }
    }

    // wave reductions
#pragma unroll
    for (int off = 32; off; off >>= 1) ls += __shfl_xor(ls, off, 64);
#pragma unroll
    for (int off = 1; off < 64; off <<= 1) {
        float b0 = __shfl_xor(v0, off, 64), b1 = __shfl_xor(v1, off, 64);
        int  bi0 = __shfl_xor(i0, off, 64), bi1 = __shfl_xor(i1, off, 64);
        top2_merge(v0, i0, v1, i1, b0, bi0, b1, bi1);
    }
#pragma unroll
    for (int off = 1; off < 64; off <<= 1) {
        float ov = __shfl_xor(av, off, 64), oraw = __shfl_xor(araw, off, 64);
        int   oi = __shfl_xor(ai, off, 64);
        if (ov > av || (ov == av && oi < ai)) { av = ov; ai = oi; araw = oraw; }
    }
    if (l == 0) {
        sws[w] = ls;
        st0v[w] = v0; st0i[w] = i0; st1v[w] = v1; st1i[w] = i1;
        sav[w] = av; sai[w] = ai; sar[w] = araw;
    }
    __syncthreads();

    const float rs = (sws[0] + sws[1]) + (sws[2] + sws[3]);
    const float rsinv = 1.0f / rs;

    float T0 = -INFINITY, T1 = -INFINITY; int I0 = 0x7fffffff, I1 = 0x7fffffff;
#pragma unroll
    for (int ww = 0; ww < 4; ++ww)
        top2_merge(T0, I0, T1, I1, st0v[ww], st0i[ww], st1v[ww], st1i[ww]);

    float AV = -INFINITY, AR = 0.0f; int AI = 0x7fffffff;
#pragma unroll
    for (int ww = 0; ww < 4; ++ww) {
        if (sav[ww] > AV || (sav[ww] == AV && sai[ww] < AI)) { AV = sav[ww]; AI = sai[ww]; AR = sar[ww]; }
    }

    // --- losses ---
    float qv = out0[(size_t)i * (2 * D) + t];
    float pv = memory[(size_t)I0 * D + t];
    float nv = memory[(size_t)I1 * D + t];
    float dq = qv - pv;
    float g  = dq * dq;
    float dp = dq + 1e-6f;          dp *= dp;
    float dn = (qv - nv) + 1e-6f;   dn *= dn;
#pragma unroll
    for (int off = 32; off; off >>= 1) {
        g  += __shfl_xor(g, off, 64);
        dp += __shfl_xor(dp, off, 64);
        dn += __shfl_xor(dn, off, 64);
    }
    if (l == 0) { sg[w] = g; sdp[w] = dp; sdn[w] = dn; }
    __syncthreads();
    if (t == 0) {
        float gs  = (sg[0] + sg[1]) + (sg[2] + sg[3]);
        float dps = (sdp[0] + sdp[1]) + (sdp[2] + sdp[3]);
        float dns = (sdn[0] + sdn[1]) + (sdn[2] + sdn[3]);
        gpart[i] = gs;
        spart[i] = fmaxf(sqrtf(dps) - sqrtf(dns) + 1.0f, 0.0f);
        jstarA[i] = AI;
        wA[i] = __expf(AR - colM[AI]);
    }

    // --- softmax transforms, vectorized stores ---
    float oq[8], om[8];
#pragma unroll
    for (int k = 0; k < 8; ++k) {
        oq[k] = __expf(v[k] - cMv[k]) * cSv[k];
        om[k] = __expf(v[k] - rm) * rsinv;
    }
    float4 q0 = {oq[0], oq[1], oq[2], oq[3]}, q1 = {oq[4], oq[5], oq[6], oq[7]};
    float4 m0 = {om[0], om[1], om[2], om[3]}, m1 = {om[4], om[5], om[6], om[7]};
    *(float4*)(row + jb) = q0;
    *(float4*)(row + jb + 4) = q1;
    *(float4*)(sm + (size_t)i * MSLOT + jb) = m0;
    *(float4*)(sm + (size_t)i * MSLOT + jb + 4) = m1;
    f16x8 h;
#pragma unroll
    for (int k = 0; k < 8; ++k) h[k] = (f16)om[k];
    *(f16x8*)(pf16 + (size_t)i * MSLOT + jb) = h;
}

// ---------------------------------------------------------------- segment sum (atomic scatter, f16 source)
__global__ __launch_bounds__(256) void k_scatter(const f16* __restrict__ qh,
                                                 const f16* __restrict__ ql,
                                                 const int* __restrict__ jstarA,
                                                 const float* __restrict__ wA,
                                                 float* __restrict__ qupd)
{
    const int i = blockIdx.x, t = threadIdx.x;
    const int j = jstarA[i];
    const float wv = wA[i] * (1.0f / 256.0f);
    float qv = (float)qh[(size_t)i * D + t] + (float)ql[(size_t)i * D + t];
    unsafeAtomicAdd(&qupd[(size_t)j * D + t], wv * qv);
}

// ---------------------------------------------------------------- updated memory
__global__ __launch_bounds__(256) void k_updmem(const float* __restrict__ qupd,
                                                const float* __restrict__ memory,
                                                float* __restrict__ out1)
{
    __shared__ float sbuf[4];
    const int j = blockIdx.x, t = threadIdx.x;
    float v = qupd[(size_t)j * D + t] + memory[(size_t)j * D + t];
    float ss = v * v;
#pragma unroll
    for (int off = 32; off; off >>= 1) ss += __shfl_xor(ss, off, 64);
    if ((t & 63) == 0) sbuf[t >> 6] = ss;
    __syncthreads();
    float tot = (sbuf[0] + sbuf[1]) + (sbuf[2] + sbuf[3]);
    float n = fmaxf(sqrtf(tot), 1e-12f);
    out1[(size_t)j * D + t] = v / n;
}

// ---------------------------------------------------------------- concat GEMM: out0 right = sfxm(f16) @ memT
// 128x256 tile, 2-phase double-buffered, pure f16 staging via global_load_lds.
__global__ __launch_bounds__(256) void k_concat(const f16* __restrict__ P,     // [BS][2048]
                                                const f16* __restrict__ memT,  // [256][2048]
                                                float* __restrict__ out0)
{
    __shared__ __align__(16) f16 As[2][4096];  // 128 r x 32 k
    __shared__ __align__(16) f16 Bs[2][8192];  // 256 n x 32 k
    const int t = threadIdx.x;
    const int l = t & 63, w = t >> 6;
    const int lk = l >> 4, lm = l & 15;
    const int i0 = blockIdx.x * 128;

#define STAGE_CC(buf, k0)                                                        \
    {                                                                            \
        _Pragma("unroll")                                                        \
        for (int c = 0; c < 2; ++c) {                                            \
            int s = c * 256 + t;                                                 \
            int r = s >> 2, cc = s & 3;                                          \
            int scc = cc ^ ((r >> 1) & 3);                                       \
            lds_cp16(&As[buf][s * 8], P + (size_t)(i0 + r) * MSLOT + (k0) + scc * 8); \
        }                                                                        \
        _Pragma("unroll")                                                        \
        for (int c = 0; c < 4; ++c) {                                            \
            int s = c * 256 + t;                                                 \
            int n = s >> 2, cc = s & 3;                                          \
            int scc = cc ^ ((n >> 1) & 3);                                       \
            lds_cp16(&Bs[buf][s * 8], memT + (size_t)n * MSLOT + (k0) + scc * 8); \
        }                                                                        \
    }

    f32x4 acc[2][16] = {};
    STAGE_CC(0, 0);
    __syncthreads();

    for (int ks = 0; ks < 64; ++ks) {
        const int cur = ks & 1;
        if (ks < 63) STAGE_CC(cur ^ 1, (ks + 1) * 32);

        f16x8 af[2];
#pragma unroll
        for (int m = 0; m < 2; ++m) {
            int r = w * 32 + m * 16 + lm;
            int off = r * 64 + ((lk ^ ((r >> 1) & 3)) << 4);
            af[m] = *(const f16x8*)((const char*)As[cur] + off);
        }
#pragma unroll
        for (int hh = 0; hh < 2; ++hh) {
            f16x8 bf[8];
#pragma unroll
            for (int n = 0; n < 8; ++n) {
                int r = (hh * 8 + n) * 16 + lm;
                int off = r * 64 + ((lk ^ ((r >> 1) & 3)) << 4);
                bf[n] = *(const f16x8*)((const char*)Bs[cur] + off);
            }
#pragma unroll
            for (int m = 0; m < 2; ++m)
#pragma unroll
                for (int n = 0; n < 8; ++n)
                    acc[m][hh * 8 + n] = __builtin_amdgcn_mfma_f32_16x16x32_f16(af[m], bf[n], acc[m][hh * 8 + n], 0, 0, 0);
        }
        __syncthreads();
    }
#undef STAGE_CC

#pragma unroll
    for (int m = 0; m < 2; ++m) {
        int row = i0 + w * 32 + m * 16 + lk * 4;
#pragma unroll
        for (int n = 0; n < 16; ++n) {
            int col = n * 16 + lm;
#pragma unroll
            for (int r = 0; r < 4; ++r)
                out0[(size_t)(row + r) * (2 * D) + D + col] = acc[m][n][r];
        }
    }
}

// ---------------------------------------------------------------- loss reduce
__global__ __launch_bounds__(256) void k_losses(const float* __restrict__ gpart,
                                                const float* __restrict__ spart,
                                                float* __restrict__ out45)
{
    __shared__ float sf[256];
    const int t = threadIdx.x;
    float g = 0.f, s = 0.f;
    for (int i = t; i < BS; i += 256) { g += gpart[i]; s += spart[i]; }
    sf[t] = g; __syncthreads();
    for (int off = 128; off; off >>= 1) { if (t < off) sf[t] += sf[t + off]; __syncthreads(); }
    float gt = sf[0]; __syncthreads();
    sf[t] = s; __syncthreads();
    for (int off = 128; off; off >>= 1) { if (t < off) sf[t] += sf[t + off]; __syncthreads(); }
    float st = sf[0];
    if (t == 0) {
        out45[0] = gt / (float)((size_t)BS * D);
        out45[1] = st / (float)BS;
    }
}

// ---------------------------------------------------------------- launcher
extern "C" void kernel_launch(void* const* d_in, const int* in_sizes, int n_in,
                              void* d_out, int out_size, void* d_ws, size_t ws_size,
                              hipStream_t stream)
{
    const float* query  = (const float*)d_in[0];
    const float* memory = (const float*)d_in[1];

    float* out  = (float*)d_out;
    float* out0 = out;                                   // update_query  [BS][2D]
    float* out1 = out0 + (size_t)BS * 2 * D;             // updated_memory[M][D]
    float* out2 = out1 + (size_t)MSLOT * D;              // sfx_score_query [BS][M]
    float* out3 = out2 + (size_t)BS * MSLOT;             // sfx_score_memory[BS][M]
    float* out45 = out3 + (size_t)BS * MSLOT;            // two scalars

    f16* qh   = (f16*)d_ws;                              // BS*D
    f16* ql   = qh + (size_t)BS * D;                     // BS*D
    f16* mh   = ql + (size_t)BS * D;                     // M*D
    f16* ml   = mh + (size_t)MSLOT * D;                  // M*D
    f16* memT = ml + (size_t)MSLOT * D;                  // D*M
    f16* pf16 = memT + (size_t)D * MSLOT;                // BS*M (sfxm f16)
    float* colpart = (float*)(pf16 + (size_t)BS * MSLOT);// NCHUNK*M*2
    float* colM    = colpart + (size_t)NCHUNK * MSLOT * 2;
    float* colSinv = colM + MSLOT;
    float* colC    = colSinv + MSLOT;
    float* wA      = colC + MSLOT;                       // BS
    int*   jstarA  = (int*)(wA + BS);                    // BS
    float* gpart   = (float*)(jstarA + BS);              // BS
    float* spart   = gpart + BS;                         // BS
    float* qupd    = spart + BS;                         // M*D

    // 1) prep (prepm also zeroes qupd — no memset node in graph)
    k_prepq<<<BS, 256, 0, stream>>>(query, out0, qh, ql);
    k_prepm<<<MSLOT, 256, 0, stream>>>(memory, mh, ml, memT, qupd);

    // 2) score GEMM (f16x2 x3 MFMA, 2-phase dbuf) + fused column partials
    k_score<<<dim3(MSLOT / 128, BS / 128), 256, 0, stream>>>(qh, ql, mh, ml, out2, colpart);

    // 3) column merge
    k_colmerge<<<MSLOT / 256, 256, 0, stream>>>(colpart, colM, colSinv, colC);

    // 4) fused row pass + softmax transforms (+ sfxm f16 copy)
    k_rowtrans<<<BS, 256, 0, stream>>>(out2, out3, pf16, colM, colSinv, colC, out0, memory,
                                       jstarA, wA, gpart, spart);

    // 5) segment-sum memory update
    k_scatter<<<BS, 256, 0, stream>>>(qh, ql, jstarA, wA, qupd);
    k_updmem<<<MSLOT, 256, 0, stream>>>(qupd, memory, out1);

    // 6) concat GEMM (f16 MFMA, 128x256 tile, 2-phase dbuf)
    k_concat<<<BS / 128, 256, 0, stream>>>(pf16, memT, out0);

    // 7) losses
    k_losses<<<1, 256, 0, stream>>>(gpart, spart, out45);
}

// Round 4
// 578.220 us; speedup vs baseline: 1.1084x; 1.1084x over previous
//
#include <hip/hip_runtime.h>
#include <hip/hip_bf16.h>
#include <cstddef>
#include <cstdint>

#define BS 32768
#define MSLOT 2048
#define D 256
#define NCHUNK 128   // i-tiles of 256 rows in k_score

typedef _Float16 f16;
typedef _Float16 f16x8 __attribute__((ext_vector_type(8)));
typedef float f32x4 __attribute__((ext_vector_type(4)));

#define WAITV(n) asm volatile("s_waitcnt vmcnt(" #n ")" ::: "memory")

__device__ __forceinline__ void barrier_raw() {
    asm volatile("" ::: "memory");
    __builtin_amdgcn_s_barrier();
    asm volatile("" ::: "memory");
}

__device__ __forceinline__ void lds_cp16(void* dst, const void* src) {
    __builtin_amdgcn_global_load_lds(
        (const __attribute__((address_space(1))) void*)src,
        (__attribute__((address_space(3))) void*)dst, 16, 0, 0);
}

__device__ __forceinline__ void top2_merge(float& a0, int& ai0, float& a1, int& ai1,
                                           float b0, int bi0, float b1, int bi1)
{
    bool bt = (b0 > a0) || (b0 == a0 && bi0 < ai0);
    float n0, n1; int ni0, ni1;
    if (bt) {
        n0 = b0; ni0 = bi0;
        bool s2 = (b1 > a0) || (b1 == a0 && bi1 < ai0);
        n1 = s2 ? b1 : a0; ni1 = s2 ? bi1 : ai0;
    } else {
        n0 = a0; ni0 = ai0;
        bool s2 = (b0 > a1) || (b0 == a1 && bi0 < ai1);
        n1 = s2 ? b0 : a1; ni1 = s2 ? bi0 : ai1;
    }
    a0 = n0; ai0 = ni0; a1 = n1; ai1 = ni1;
}

// ---------------------------------------------------------------- prep: normalize + f16x2 split (q scaled by 256)
// qcat layout: [BS][512] = [qh(256) | ql(256)]
__global__ __launch_bounds__(256) void k_prepq(const float* __restrict__ query,
                                               float* __restrict__ out0,
                                               f16* __restrict__ qcat)
{
    __shared__ float sbuf[4];
    const int i = blockIdx.x, t = threadIdx.x;
    float v = query[(size_t)i * D + t];
    float ss = v * v;
#pragma unroll
    for (int off = 32; off; off >>= 1) ss += __shfl_xor(ss, off, 64);
    if ((t & 63) == 0) sbuf[t >> 6] = ss;
    __syncthreads();
    float tot = (sbuf[0] + sbuf[1]) + (sbuf[2] + sbuf[3]);
    float n = fmaxf(sqrtf(tot), 1e-12f);
    float qv = v / n;
    out0[(size_t)i * (2 * D) + t] = qv;
    float qs = qv * 256.0f;
    f16 h = (f16)qs;
    f16 lo = (f16)(qs - (float)h);
    qcat[(size_t)i * 512 + t] = h;
    qcat[(size_t)i * 512 + 256 + t] = lo;
}

// ---------------------------------------------------------------- prep: memory split + f16 transpose + zero qupd
// mcat layout: [M][512] = [mh(256) | ml(256)]
__global__ __launch_bounds__(256) void k_prepm(const float* __restrict__ memory,
                                               f16* __restrict__ mcat,
                                               f16* __restrict__ memT,
                                               float* __restrict__ qupd)
{
    const int j = blockIdx.x, t = threadIdx.x;
    float m = memory[(size_t)j * D + t];
    f16 h = (f16)m;
    f16 lo = (f16)(m - (float)h);
    mcat[(size_t)j * 512 + t] = h;
    mcat[(size_t)j * 512 + 256 + t] = lo;
    memT[(size_t)t * MSLOT + j] = h;   // [n=dim][k=slot]
    qupd[(size_t)j * D + t] = 0.0f;
}

// ---------------------------------------------------------------- score GEMM
// Logical K=768: A = [qh | qh | ql], B = [mh | ml | mh]  ->  qh*mh + qh*ml + ql*mh = 256*score.
// 256x256 tile, 8 waves (512 thr), BK=64, counted-vmcnt pipeline (raw barriers, vmcnt(8) steady).
__global__ __launch_bounds__(512, 2) void k_score(const f16* __restrict__ qcat,
                                                  const f16* __restrict__ mcat,
                                                  float* __restrict__ out2,
                                                  float* __restrict__ colpart)
{
    __shared__ __align__(16) f16 As[2][256 * 64];   // 32 KB per buf
    __shared__ __align__(16) f16 Bs[2][256 * 64];
    __shared__ float sepM[8][4][16], sepS[8][4][16];

    const int tid = threadIdx.x;
    const int l = tid & 63, w = tid >> 6;
    const int wr = w >> 2, wc = w & 3;              // 2 row-halves x 4 col-quarters
    const int lk = (l >> 4) & 3, lm = l & 15;
    const int sr = tid >> 3, sch = tid & 7;         // stage row-part / chunk

    // XCD-aware swizzle: keep all 8 j-tiles of an i-tile on one XCD (A-panel L2 reuse)
    const int hflat = blockIdx.y * 8 + blockIdx.x;  // 1024 blocks
    const int xcd = hflat & 7, kk8 = hflat >> 3;    // kk8 in 0..127
    const int by = xcd * 16 + (kk8 >> 3);           // i-tile 0..127
    const int bx = kk8 & 7;                         // j-tile 0..7
    const int i0 = by * 256, j0 = bx * 256;

#define STAGE(buf, t) do {                                                          \
    int k0_ = (t) * 64;                                                             \
    int ao_ = ((t) < 8 ? 0 : 256) + (k0_ & 255);                                    \
    int bo_ = ((((t) >= 4) && ((t) < 8)) ? 256 : 0) + (k0_ & 255);                  \
    _Pragma("unroll")                                                               \
    for (int c = 0; c < 4; ++c) {                                                   \
        int r_ = c * 64 + sr;                                                       \
        int g_ = sch ^ ((r_ >> 1) & 7);                                             \
        lds_cp16(&As[buf][(c * 512 + tid) * 8],                                     \
                 qcat + (size_t)(i0 + r_) * 512 + ao_ + g_ * 8);                    \
        lds_cp16(&Bs[buf][(c * 512 + tid) * 8],                                     \
                 mcat + (size_t)(j0 + r_) * 512 + bo_ + g_ * 8);                    \
    }                                                                               \
} while (0)

    f32x4 acc[8][4] = {};

    STAGE(0, 0);
    STAGE(1, 1);

    for (int t = 0; t < 12; ++t) {
        const int cur = t & 1;
        if (t < 11) { WAITV(8); } else { WAITV(0); }
        barrier_raw();
        const f16* Ab = As[cur];
        const f16* Bb = Bs[cur];
        __builtin_amdgcn_s_setprio(1);
#pragma unroll
        for (int kk = 0; kk < 2; ++kk) {
            f16x8 bf[4];
#pragma unroll
            for (int ni = 0; ni < 4; ++ni) {
                int r = wc * 64 + ni * 16 + lm;
                int slot = (kk * 4 + lk) ^ (lm >> 1);
                bf[ni] = *(const f16x8*)(Bb + r * 64 + slot * 8);
            }
#pragma unroll
            for (int mi = 0; mi < 8; ++mi) {
                int r = wr * 128 + mi * 16 + lm;
                int slot = (kk * 4 + lk) ^ (lm >> 1);
                f16x8 af = *(const f16x8*)(Ab + r * 64 + slot * 8);
#pragma unroll
                for (int ni = 0; ni < 4; ++ni)
                    acc[mi][ni] = __builtin_amdgcn_mfma_f32_16x16x32_f16(af, bf[ni], acc[mi][ni], 0, 0, 0);
            }
        }
        __builtin_amdgcn_s_setprio(0);
        barrier_raw();
        if (t < 10) STAGE(cur, t + 2);
    }
#undef STAGE

    // scale back (q was pre-scaled by 256)
    const float sc = 1.0f / 256.0f;
#pragma unroll
    for (int mi = 0; mi < 8; ++mi)
#pragma unroll
        for (int ni = 0; ni < 4; ++ni)
            acc[mi][ni] *= sc;

    // store raw score
#pragma unroll
    for (int mi = 0; mi < 8; ++mi) {
        int row = i0 + wr * 128 + mi * 16 + lk * 4;
#pragma unroll
        for (int ni = 0; ni < 4; ++ni) {
            int col = j0 + wc * 64 + ni * 16 + lm;
#pragma unroll
            for (int r = 0; r < 4; ++r)
                out2[(size_t)(row + r) * MSLOT + col] = acc[mi][ni][r];
        }
    }

    // fused column partials over this block's 256 rows
    float cm[4], cs[4];
#pragma unroll
    for (int ni = 0; ni < 4; ++ni) {
        float mx = -INFINITY;
#pragma unroll
        for (int mi = 0; mi < 8; ++mi)
#pragma unroll
            for (int r = 0; r < 4; ++r) mx = fmaxf(mx, acc[mi][ni][r]);
        float sm = 0.0f;
#pragma unroll
        for (int mi = 0; mi < 8; ++mi)
#pragma unroll
            for (int r = 0; r < 4; ++r) sm += __expf(acc[mi][ni][r] - mx);
        // merge across lk groups (lane bits 4,5)
#pragma unroll
        for (int off = 16; off <= 32; off <<= 1) {
            float om = __shfl_xor(mx, off, 64);
            float os = __shfl_xor(sm, off, 64);
            float nm = fmaxf(mx, om);
            sm = sm * __expf(mx - nm) + os * __expf(om - nm);
            mx = nm;
        }
        cm[ni] = mx; cs[ni] = sm;
    }
    if (l < 16) {
#pragma unroll
        for (int ni = 0; ni < 4; ++ni) { sepM[w][ni][l] = cm[ni]; sepS[w][ni][l] = cs[ni]; }
    }
    __syncthreads();
    if (w < 4 && l < 16) {
#pragma unroll
        for (int ni = 0; ni < 4; ++ni) {
            float m1 = sepM[w][ni][l], s1 = sepS[w][ni][l];
            float m2 = sepM[w + 4][ni][l], s2 = sepS[w + 4][ni][l];
            float nm = fmaxf(m1, m2);
            float ns = s1 * __expf(m1 - nm) + s2 * __expf(m2 - nm);
            int col = j0 + w * 64 + ni * 16 + l;
            size_t o = ((size_t)by * MSLOT + col) * 2;
            colpart[o + 0] = nm;
            colpart[o + 1] = ns;
        }
    }
}

// ---------------------------------------------------------------- column merge
__global__ __launch_bounds__(256) void k_colmerge(const float* __restrict__ colpart,
                                                  float* __restrict__ colM,
                                                  float* __restrict__ colSinv,
                                                  float* __restrict__ colC)
{
    const int col = blockIdx.x * 256 + threadIdx.x;
    float m = -INFINITY, s = 0.0f;
    for (int c = 0; c < NCHUNK; ++c) {
        size_t o = ((size_t)c * MSLOT + col) * 2;
        float pm = colpart[o + 0], ps = colpart[o + 1];
        float nm = fmaxf(m, pm);
        s = s * __expf(m - nm) + ps * __expf(pm - nm);
        m = nm;
    }
    colM[col] = m;
    colSinv[col] = 1.0f / s;
    colC[col] = m + __logf(s);
}

// ---------------------------------------------------------------- fused row pass + softmax transforms (vectorized)
__global__ __launch_bounds__(256) void k_rowtrans(float* __restrict__ sq,   // out2 in-place
                                                  float* __restrict__ sm,   // out3
                                                  f16* __restrict__ pf16,   // sfxm f16 copy
                                                  const float* __restrict__ colM,
                                                  const float* __restrict__ colSinv,
                                                  const float* __restrict__ colC,
                                                  const float* __restrict__ out0,   // q in left half, ld 2D
                                                  const float* __restrict__ memory,
                                                  int* __restrict__ jstarA, float* __restrict__ wA,
                                                  float* __restrict__ gpart, float* __restrict__ spart)
{
    __shared__ float swm[4], sws[4];
    __shared__ float st0v[4], st1v[4]; __shared__ int st0i[4], st1i[4];
    __shared__ float sav[4], sar[4];  __shared__ int sai[4];
    __shared__ float sg[4], sdp[4], sdn[4];

    const int i = blockIdx.x, t = threadIdx.x;
    const int l = t & 63, w = t >> 6;
    const int jb = t * 8;
    float* row = sq + (size_t)i * MSLOT;

    float v[8];
    {
        float4 va = *(const float4*)(row + jb);
        float4 vb = *(const float4*)(row + jb + 4);
        v[0] = va.x; v[1] = va.y; v[2] = va.z; v[3] = va.w;
        v[4] = vb.x; v[5] = vb.y; v[6] = vb.z; v[7] = vb.w;
    }
    float cCv[8], cMv[8], cSv[8];
    {
        float4 a = *(const float4*)(colC + jb);
        float4 b = *(const float4*)(colC + jb + 4);
        cCv[0] = a.x; cCv[1] = a.y; cCv[2] = a.z; cCv[3] = a.w;
        cCv[4] = b.x; cCv[5] = b.y; cCv[6] = b.z; cCv[7] = b.w;
        a = *(const float4*)(colM + jb); b = *(const float4*)(colM + jb + 4);
        cMv[0] = a.x; cMv[1] = a.y; cMv[2] = a.z; cMv[3] = a.w;
        cMv[4] = b.x; cMv[5] = b.y; cMv[6] = b.z; cMv[7] = b.w;
        a = *(const float4*)(colSinv + jb); b = *(const float4*)(colSinv + jb + 4);
        cSv[0] = a.x; cSv[1] = a.y; cSv[2] = a.z; cSv[3] = a.w;
        cSv[4] = b.x; cSv[5] = b.y; cSv[6] = b.z; cSv[7] = b.w;
    }

    // --- row max ---
    float lmx = v[0];
#pragma unroll
    for (int k = 1; k < 8; ++k) lmx = fmaxf(lmx, v[k]);
#pragma unroll
    for (int off = 32; off; off >>= 1) lmx = fmaxf(lmx, __shfl_xor(lmx, off, 64));
    if (l == 0) swm[w] = lmx;
    __syncthreads();
    const float rm = fmaxf(fmaxf(swm[0], swm[1]), fmaxf(swm[2], swm[3]));

    // --- per-thread: sumexp, top2(raw), argmax(col-softmax) ---
    float ls = 0.0f;
#pragma unroll
    for (int k = 0; k < 8; ++k) ls += __expf(v[k] - rm);

    float v0 = -INFINITY, v1 = -INFINITY; int i0 = 0x7fffffff, i1 = 0x7fffffff;
#pragma unroll
    for (int k = 0; k < 8; ++k) {
        int idx = jb + k; float cv = v[k];
        if (cv > v0)      { v1 = v0; i1 = i0; v0 = cv; i0 = idx; }
        else if (cv > v1) { v1 = cv; i1 = idx; }
    }

    float av = -INFINITY, araw = 0.0f; int ai = 0x7fffffff;
#pragma unroll
    for (int k = 0; k < 8; ++k) {
        int idx = jb + k;
        float x = v[k] - cCv[k];
        if (x > av) { av = x; ai = idx; araw = v[k]; }
    }

    // wave reductions
#pragma unroll
    for (int off = 32; off; off >>= 1) ls += __shfl_xor(ls, off, 64);
#pragma unroll
    for (int off = 1; off < 64; off <<= 1) {
        float b0 = __shfl_xor(v0, off, 64), b1 = __shfl_xor(v1, off, 64);
        int  bi0 = __shfl_xor(i0, off, 64), bi1 = __shfl_xor(i1, off, 64);
        top2_merge(v0, i0, v1, i1, b0, bi0, b1, bi1);
    }
#pragma unroll
    for (int off = 1; off < 64; off <<= 1) {
        float ov = __shfl_xor(av, off, 64), oraw = __shfl_xor(araw, off, 64);
        int   oi = __shfl_xor(ai, off, 64);
        if (ov > av || (ov == av && oi < ai)) { av = ov; ai = oi; araw = oraw; }
    }
    if (l == 0) {
        sws[w] = ls;
        st0v[w] = v0; st0i[w] = i0; st1v[w] = v1; st1i[w] = i1;
        sav[w] = av; sai[w] = ai; sar[w] = araw;
    }
    __syncthreads();

    const float rs = (sws[0] + sws[1]) + (sws[2] + sws[3]);
    const float rsinv = 1.0f / rs;

    float T0 = -INFINITY, T1 = -INFINITY; int I0 = 0x7fffffff, I1 = 0x7fffffff;
#pragma unroll
    for (int ww = 0; ww < 4; ++ww)
        top2_merge(T0, I0, T1, I1, st0v[ww], st0i[ww], st1v[ww], st1i[ww]);

    float AV = -INFINITY, AR = 0.0f; int AI = 0x7fffffff;
#pragma unroll
    for (int ww = 0; ww < 4; ++ww) {
        if (sav[ww] > AV || (sav[ww] == AV && sai[ww] < AI)) { AV = sav[ww]; AI = sai[ww]; AR = sar[ww]; }
    }

    // --- losses ---
    float qv = out0[(size_t)i * (2 * D) + t];
    float pv = memory[(size_t)I0 * D + t];
    float nv = memory[(size_t)I1 * D + t];
    float dq = qv - pv;
    float g  = dq * dq;
    float dp = dq + 1e-6f;          dp *= dp;
    float dn = (qv - nv) + 1e-6f;   dn *= dn;
#pragma unroll
    for (int off = 32; off; off >>= 1) {
        g  += __shfl_xor(g, off, 64);
        dp += __shfl_xor(dp, off, 64);
        dn += __shfl_xor(dn, off, 64);
    }
    if (l == 0) { sg[w] = g; sdp[w] = dp; sdn[w] = dn; }
    __syncthreads();
    if (t == 0) {
        float gs  = (sg[0] + sg[1]) + (sg[2] + sg[3]);
        float dps = (sdp[0] + sdp[1]) + (sdp[2] + sdp[3]);
        float dns = (sdn[0] + sdn[1]) + (sdn[2] + sdn[3]);
        gpart[i] = gs;
        spart[i] = fmaxf(sqrtf(dps) - sqrtf(dns) + 1.0f, 0.0f);
        jstarA[i] = AI;
        wA[i] = __expf(AR - colM[AI]);
    }

    // --- softmax transforms, vectorized stores ---
    float oq[8], om[8];
#pragma unroll
    for (int k = 0; k < 8; ++k) {
        oq[k] = __expf(v[k] - cMv[k]) * cSv[k];
        om[k] = __expf(v[k] - rm) * rsinv;
    }
    float4 q0 = {oq[0], oq[1], oq[2], oq[3]}, q1 = {oq[4], oq[5], oq[6], oq[7]};
    float4 m0 = {om[0], om[1], om[2], om[3]}, m1 = {om[4], om[5], om[6], om[7]};
    *(float4*)(row + jb) = q0;
    *(float4*)(row + jb + 4) = q1;
    *(float4*)(sm + (size_t)i * MSLOT + jb) = m0;
    *(float4*)(sm + (size_t)i * MSLOT + jb + 4) = m1;
    f16x8 h;
#pragma unroll
    for (int k = 0; k < 8; ++k) h[k] = (f16)om[k];
    *(f16x8*)(pf16 + (size_t)i * MSLOT + jb) = h;
}

// ---------------------------------------------------------------- segment sum (atomic scatter, f16 source)
__global__ __launch_bounds__(256) void k_scatter(const f16* __restrict__ qcat,
                                                 const int* __restrict__ jstarA,
                                                 const float* __restrict__ wA,
                                                 float* __restrict__ qupd)
{
    const int i = blockIdx.x, t = threadIdx.x;
    const int j = jstarA[i];
    const float wv = wA[i] * (1.0f / 256.0f);
    float qv = (float)qcat[(size_t)i * 512 + t] + (float)qcat[(size_t)i * 512 + 256 + t];
    unsafeAtomicAdd(&qupd[(size_t)j * D + t], wv * qv);
}

// ---------------------------------------------------------------- updated memory
__global__ __launch_bounds__(256) void k_updmem(const float* __restrict__ qupd,
                                                const float* __restrict__ memory,
                                                float* __restrict__ out1)
{
    __shared__ float sbuf[4];
    const int j = blockIdx.x, t = threadIdx.x;
    float v = qupd[(size_t)j * D + t] + memory[(size_t)j * D + t];
    float ss = v * v;
#pragma unroll
    for (int off = 32; off; off >>= 1) ss += __shfl_xor(ss, off, 64);
    if ((t & 63) == 0) sbuf[t >> 6] = ss;
    __syncthreads();
    float tot = (sbuf[0] + sbuf[1]) + (sbuf[2] + sbuf[3]);
    float n = fmaxf(sqrtf(tot), 1e-12f);
    out1[(size_t)j * D + t] = v / n;
}

// ---------------------------------------------------------------- concat GEMM: out0 right = sfxm(f16) @ memT
// 128x256 tile, 8 waves, BK=64, counted-vmcnt pipeline (vmcnt(6) steady).
__global__ __launch_bounds__(512, 2) void k_concat(const f16* __restrict__ P,     // [BS][2048]
                                                   const f16* __restrict__ memT,  // [256][2048]
                                                   float* __restrict__ out0)
{
    __shared__ __align__(16) f16 As[2][128 * 64];   // 16 KB per buf
    __shared__ __align__(16) f16 Bs[2][256 * 64];   // 32 KB per buf
    const int tid = threadIdx.x;
    const int l = tid & 63, w = tid >> 6;
    const int wr = w >> 2, wc = w & 3;
    const int lk = (l >> 4) & 3, lm = l & 15;
    const int sr = tid >> 3, sch = tid & 7;
    const int i0 = blockIdx.x * 128;

#define STAGE_CC(buf, t) do {                                                       \
    int k0_ = (t) * 64;                                                             \
    _Pragma("unroll")                                                               \
    for (int c = 0; c < 2; ++c) {                                                   \
        int r_ = c * 64 + sr;                                                       \
        int g_ = sch ^ ((r_ >> 1) & 7);                                             \
        lds_cp16(&As[buf][(c * 512 + tid) * 8],                                     \
                 P + (size_t)(i0 + r_) * MSLOT + k0_ + g_ * 8);                     \
    }                                                                               \
    _Pragma("unroll")                                                               \
    for (int c = 0; c < 4; ++c) {                                                   \
        int r_ = c * 64 + sr;                                                       \
        int g_ = sch ^ ((r_ >> 1) & 7);                                             \
        lds_cp16(&Bs[buf][(c * 512 + tid) * 8],                                     \
                 memT + (size_t)r_ * MSLOT + k0_ + g_ * 8);                         \
    }                                                                               \
} while (0)

    f32x4 acc[4][4] = {};

    STAGE_CC(0, 0);
    STAGE_CC(1, 1);

    for (int t = 0; t < 32; ++t) {
        const int cur = t & 1;
        if (t < 31) { WAITV(6); } else { WAITV(0); }
        barrier_raw();
        const f16* Ab = As[cur];
        const f16* Bb = Bs[cur];
        __builtin_amdgcn_s_setprio(1);
#pragma unroll
        for (int kk = 0; kk < 2; ++kk) {
            f16x8 bf[4];
#pragma unroll
            for (int ni = 0; ni < 4; ++ni) {
                int r = wc * 64 + ni * 16 + lm;
                int slot = (kk * 4 + lk) ^ (lm >> 1);
                bf[ni] = *(const f16x8*)(Bb + r * 64 + slot * 8);
            }
#pragma unroll
            for (int mi = 0; mi < 4; ++mi) {
                int r = wr * 64 + mi * 16 + lm;
                int slot = (kk * 4 + lk) ^ (lm >> 1);
                f16x8 af = *(const f16x8*)(Ab + r * 64 + slot * 8);
#pragma unroll
                for (int ni = 0; ni < 4; ++ni)
                    acc[mi][ni] = __builtin_amdgcn_mfma_f32_16x16x32_f16(af, bf[ni], acc[mi][ni], 0, 0, 0);
            }
        }
        __builtin_amdgcn_s_setprio(0);
        barrier_raw();
        if (t < 30) STAGE_CC(cur, t + 2);
    }
#undef STAGE_CC

#pragma unroll
    for (int mi = 0; mi < 4; ++mi) {
        int row = i0 + wr * 64 + mi * 16 + lk * 4;
#pragma unroll
        for (int ni = 0; ni < 4; ++ni) {
            int col = wc * 64 + ni * 16 + lm;
#pragma unroll
            for (int r = 0; r < 4; ++r)
                out0[(size_t)(row + r) * (2 * D) + D + col] = acc[mi][ni][r];
        }
    }
}

// ---------------------------------------------------------------- loss reduce
__global__ __launch_bounds__(256) void k_losses(const float* __restrict__ gpart,
                                                const float* __restrict__ spart,
                                                float* __restrict__ out45)
{
    __shared__ float sf[256];
    const int t = threadIdx.x;
    float g = 0.f, s = 0.f;
    for (int i = t; i < BS; i += 256) { g += gpart[i]; s += spart[i]; }
    sf[t] = g; __syncthreads();
    for (int off = 128; off; off >>= 1) { if (t < off) sf[t] += sf[t + off]; __syncthreads(); }
    float gt = sf[0]; __syncthreads();
    sf[t] = s; __syncthreads();
    for (int off = 128; off; off >>= 1) { if (t < off) sf[t] += sf[t + off]; __syncthreads(); }
    float st = sf[0];
    if (t == 0) {
        out45[0] = gt / (float)((size_t)BS * D);
        out45[1] = st / (float)BS;
    }
}

// ---------------------------------------------------------------- launcher
extern "C" void kernel_launch(void* const* d_in, const int* in_sizes, int n_in,
                              void* d_out, int out_size, void* d_ws, size_t ws_size,
                              hipStream_t stream)
{
    const float* query  = (const float*)d_in[0];
    const float* memory = (const float*)d_in[1];

    float* out  = (float*)d_out;
    float* out0 = out;                                   // update_query  [BS][2D]
    float* out1 = out0 + (size_t)BS * 2 * D;             // updated_memory[M][D]
    float* out2 = out1 + (size_t)MSLOT * D;              // sfx_score_query [BS][M]
    float* out3 = out2 + (size_t)BS * MSLOT;             // sfx_score_memory[BS][M]
    float* out45 = out3 + (size_t)BS * MSLOT;            // two scalars

    f16* qcat = (f16*)d_ws;                              // BS*512  [qh|ql]
    f16* mcat = qcat + (size_t)BS * 512;                 // M*512   [mh|ml]
    f16* memT = mcat + (size_t)MSLOT * 512;              // D*M
    f16* pf16 = memT + (size_t)D * MSLOT;                // BS*M (sfxm f16)
    float* colpart = (float*)(pf16 + (size_t)BS * MSLOT);// NCHUNK*M*2
    float* colM    = colpart + (size_t)NCHUNK * MSLOT * 2;
    float* colSinv = colM + MSLOT;
    float* colC    = colSinv + MSLOT;
    float* wA      = colC + MSLOT;                       // BS
    int*   jstarA  = (int*)(wA + BS);                    // BS
    float* gpart   = (float*)(jstarA + BS);              // BS
    float* spart   = gpart + BS;                         // BS
    float* qupd    = spart + BS;                         // M*D

    // 1) prep (prepm also zeroes qupd)
    k_prepq<<<BS, 256, 0, stream>>>(query, out0, qcat);
    k_prepm<<<MSLOT, 256, 0, stream>>>(memory, mcat, memT, qupd);

    // 2) score GEMM (K=768 f16 MFMA, 256^2 tile, counted-vmcnt pipeline) + col partials
    k_score<<<dim3(MSLOT / 256, BS / 256), 512, 0, stream>>>(qcat, mcat, out2, colpart);

    // 3) column merge
    k_colmerge<<<MSLOT / 256, 256, 0, stream>>>(colpart, colM, colSinv, colC);

    // 4) fused row pass + softmax transforms (+ sfxm f16 copy)
    k_rowtrans<<<BS, 256, 0, stream>>>(out2, out3, pf16, colM, colSinv, colC, out0, memory,
                                       jstarA, wA, gpart, spart);

    // 5) segment-sum memory update
    k_scatter<<<BS, 256, 0, stream>>>(qcat, jstarA, wA, qupd);
    k_updmem<<<MSLOT, 256, 0, stream>>>(qupd, memory, out1);

    // 6) concat GEMM (f16 MFMA, 128x256 tile, counted-vmcnt pipeline)
    k_concat<<<BS / 128, 512, 0, stream>>>(pf16, memT, out0);

    // 7) losses
    k_losses<<<1, 256, 0, stream>>>(gpart, spart, out45);
}